// Round 8
// baseline (259.786 us; speedup 1.0000x reference)
//
#include <hip/hip_runtime.h>

// Cumulative max along H for x:(32,1,1024,1024) fp32 — contiguous-streaming
// 3-pass. Round-7 post-mortem: every variant touching x in 128-256B granules
// at 4KB stride caps at ~2.4 TB/s (fill kernel: 6.7 TB/s contiguous), and the
// per-chunk __syncthreads forced vmcnt(0) drains that made prefetch moot.
// This version: block (b, hseg) of 256 threads streams CONTIGUOUS 64KB
// (thread tid = float4 #tid of each 4KB row; scan is per-column independent,
// so zero intra-segment communication — no LDS, no shuffles, no barriers).
// Carry across the 64 h-segments via a tiny middle prefix pass on 8MiB ws.

constexpr int B = 32;
constexpr int H = 1024;
constexpr int W = 1024;
constexpr int ROW4 = W / 4;          // 256 float4 per row
constexpr int NSEG = 64;             // h-segments per column
constexpr int R = H / NSEG;          // 16 rows per segment
constexpr int NT = 256;              // threads per block = float4 per row
constexpr int NCOL = B * W;          // 32768 scalar columns

__device__ __forceinline__ float4 max4(float4 a, float4 b) {
    return make_float4(fmaxf(a.x, b.x), fmaxf(a.y, b.y),
                       fmaxf(a.z, b.z), fmaxf(a.w, b.w));
}

// K1: block bs=(b*NSEG+s) -> per-thread max over its 16 rows (independent
// loads, block streams contiguous 64KB), write 4KB segmax row.
__global__ __launch_bounds__(256) void k1_segmax(const float4* __restrict__ x4,
                                                 float4* __restrict__ ws4) {
    const int bs = blockIdx.x;                    // 0..B*NSEG-1
    const int tid = threadIdx.x;
    const size_t base = (size_t)bs * R * ROW4 + tid;  // b*H*ROW4 + s*R*ROW4 + tid
    float4 m = x4[base];
#pragma unroll
    for (int r = 1; r < R; ++r) m = max4(m, x4[base + (size_t)r * ROW4]);
    ws4[(size_t)bs * ROW4 + tid] = m;
}

// K2: exclusive prefix-max over the 64 segment maxes, one thread per scalar
// column (consecutive threads -> consecutive addresses each step).
__global__ __launch_bounds__(256) void k2_prefix(float* __restrict__ wsf) {
    const int t = blockIdx.x * 256 + threadIdx.x;  // 0..NCOL-1
    const int b = t >> 10;                          // column's b
    const int w = t & (W - 1);
    float run = -__builtin_inff();
#pragma unroll
    for (int s = 0; s < NSEG; ++s) {
        const size_t i = ((size_t)(b * NSEG + s)) * W + w;
        float v = wsf[i];
        wsf[i] = run;                               // exclusive
        run = fmaxf(run, v);
    }
}

// K3: carry-in + running max over 16 rows; contiguous 64KB read + 64KB write.
__global__ __launch_bounds__(256) void k3_apply(const float4* __restrict__ x4,
                                                float4* __restrict__ o4,
                                                const float4* __restrict__ ws4) {
    const int bs = blockIdx.x;
    const int tid = threadIdx.x;
    const size_t base = (size_t)bs * R * ROW4 + tid;
    float4 a = ws4[(size_t)bs * ROW4 + tid];
#pragma unroll
    for (int r = 0; r < R; ++r) {
        a = max4(a, x4[base + (size_t)r * ROW4]);
        o4[base + (size_t)r * ROW4] = a;
    }
}

extern "C" void kernel_launch(void* const* d_in, const int* in_sizes, int n_in,
                              void* d_out, int out_size, void* d_ws, size_t ws_size,
                              hipStream_t stream) {
    const float4* x4 = (const float4*)d_in[0];
    float4* o4 = (float4*)d_out;

    k1_segmax<<<B * NSEG, NT, 0, stream>>>(x4, (float4*)d_ws);
    k2_prefix<<<NCOL / 256, 256, 0, stream>>>((float*)d_ws);
    k3_apply<<<B * NSEG, NT, 0, stream>>>(x4, o4, (const float4*)d_ws);
}